// Round 7
// baseline (207.591 us; speedup 1.0000x reference)
//
#include <hip/hip_runtime.h>
#include <hip/hip_cooperative_groups.h>

namespace cg = cooperative_groups;

#define NHEADS 16
#define NW 8
#define SEQ 1024
#define BATCH 8
#define EMB 128
#define PW 132                  // proj LDS row stride (floats): 132 mod 32 = 4 -> disjoint bank quads
#define KQ4 257                 // float4 stride per key-quarter (bank-staggers quarters by 4)
#define PLANE 1028              // float4 offset of plane B (= 4*257)

typedef _Float16 half8 __attribute__((ext_vector_type(8)));

// quantum_heads closed form for one (b,s,head) row (fp32 input):
// c[w] = cos(x[w] + theta[w]); z[0] = c1..c7; z[w>=1] = c0..cw
__device__ __forceinline__ void qrow(const float* __restrict__ xp,
                                     const float* __restrict__ th, float* z) {
    float4 a = *reinterpret_cast<const float4*>(xp);
    float4 b = *reinterpret_cast<const float4*>(xp + 4);
    float c0 = __cosf(a.x + th[0]);
    float c1 = __cosf(a.y + th[1]);
    float c2 = __cosf(a.z + th[2]);
    float c3 = __cosf(a.w + th[3]);
    float c4 = __cosf(b.x + th[4]);
    float c5 = __cosf(b.y + th[5]);
    float c6 = __cosf(b.z + th[6]);
    float c7 = __cosf(b.w + th[7]);
    float u = c1 * c2;
    u *= c3; u *= c4; u *= c5; u *= c6; u *= c7;
    z[0] = u;
    z[1] = c0 * c1;
    z[2] = z[1] * c2;
    z[3] = z[2] * c3;
    z[4] = z[3] * c4;
    z[5] = z[4] * c5;
    z[6] = z[5] * c6;
    z[7] = z[6] * c7;
}

// ---------------- fused cooperative kernel: attention then projection -------
// grid = 1024 blocks x 256 threads; LDS 33.8KB -> 4 blocks/CU co-resident.
__global__ __launch_bounds__(256, 4) void fused_attn_proj(
    const float* __restrict__ x,
    const float* __restrict__ theta,
    const float* __restrict__ W,
    const float* __restrict__ bias,
    _Float16* __restrict__ P,       // [B*S][128] f16 normalized attn@h (ws)
    float* __restrict__ out)
{
    __shared__ float smem[2 * 32 * PW];     // 8448 floats = 33792 B
    const int t   = threadIdx.x;
    const int bid = blockIdx.x;

    // ============ phase 1: attention -> P ============
    {
        const int bh = bid >> 3;            // 0..127
        const int qo = bid & 7;             // which 128-query octant
        const int b  = bh >> 4, h = bh & 15;

        float th[8];
#pragma unroll
        for (int w = 0; w < 8; ++w) th[w] = theta[w];   // wave-uniform

        float4* kv4 = reinterpret_cast<float4*>(smem);
        // stage all 1024 keys; key kl lives in quarter i = kl>>8 at slot t
#pragma unroll
        for (int i = 0; i < 4; ++i) {
            const int kl = t + 256 * i;
            float z[8];
            qrow(x + ((size_t)(b * SEQ + kl) * EMB + h * NW), th, z);
            kv4[i * KQ4 + t]         = make_float4(z[0], z[1], z[2], z[3]);
            kv4[PLANE + i * KQ4 + t] = make_float4(z[4], z[5], z[6], z[7]);
        }
        __syncthreads();

        const int lane = t & 63;
        const int wv   = t >> 6;            // wave 0..3
        const int lq   = lane & 15;         // query within wave
        const int kq   = lane >> 4;         // key-quarter 0..3
        const float QS = 0.35355339059327373f * 1.4426950408889634f;
        const float4* Ap = kv4 + kq * KQ4;          // quarters on disjoint bank quads
        const float4* Bp = kv4 + PLANE + kq * KQ4;

        for (int ps = 0; ps < 2; ++ps) {
            const int sq = qo * 128 + ps * 64 + wv * 16 + lq;
            float qv[8], oacc[8];
            {
                float z[8];
                qrow(x + ((size_t)(b * SEQ + sq) * EMB + h * NW), th, z);
#pragma unroll
                for (int d = 0; d < 8; ++d) { qv[d] = z[d] * QS; oacc[d] = 0.f; }
            }
            float lac = 0.f;

#pragma unroll 4
            for (int k = 0; k < 256; ++k) {
                float4 ka = Ap[k];
                float4 kb = Bp[k];
                float s = fmaf(qv[0], ka.x, fmaf(qv[1], ka.y, fmaf(qv[2], ka.z,
                          fmaf(qv[3], ka.w, fmaf(qv[4], kb.x, fmaf(qv[5], kb.y,
                          fmaf(qv[6], kb.z, qv[7] * kb.w)))))));
                float pe = __builtin_amdgcn_exp2f(s);   // one v_exp_f32
                lac += pe;
                oacc[0] = fmaf(pe, ka.x, oacc[0]); oacc[1] = fmaf(pe, ka.y, oacc[1]);
                oacc[2] = fmaf(pe, ka.z, oacc[2]); oacc[3] = fmaf(pe, ka.w, oacc[3]);
                oacc[4] = fmaf(pe, kb.x, oacc[4]); oacc[5] = fmaf(pe, kb.y, oacc[5]);
                oacc[6] = fmaf(pe, kb.z, oacc[6]); oacc[7] = fmaf(pe, kb.w, oacc[7]);
            }

            // reduce the 4 key-quarter partners: lanes l, l^16, l^32, l^48
#pragma unroll
            for (int off = 16; off <= 32; off <<= 1) {
#pragma unroll
                for (int d = 0; d < 8; ++d) oacc[d] += __shfl_xor(oacc[d], off);
                lac += __shfl_xor(lac, off);
            }
            if (kq == 0) {                  // lanes 0..15 hold the totals
                const float inv = 1.0f / lac;
                half8 hv;
#pragma unroll
                for (int d = 0; d < 8; ++d) hv[d] = (_Float16)(oacc[d] * inv);
                *reinterpret_cast<half8*>(P + (size_t)(b * SEQ + sq) * EMB + h * NW) = hv;
            }
        }
    }

    cg::this_grid().sync();

    // ============ phase 2: out = P @ W^T + bias ============
    {
        float* Pl = smem;                   // 32 x PW
        float* Wl = smem + 32 * PW;         // 32 x PW
        const int row0  = (bid >> 2) * 32;
        const int ecol0 = (bid & 3) * 32;

        // stage P tile (f16 -> f32, coalesced half8 loads)
#pragma unroll
        for (int i = 0; i < 2; ++i) {
            const int g  = t + 256 * i;     // 512 half8 chunks
            const int r  = g >> 4;
            const int c8 = (g & 15) * 8;
            half8 hv = *reinterpret_cast<const half8*>(P + (size_t)(row0 + r) * EMB + c8);
            float4 v0 = make_float4((float)hv[0], (float)hv[1], (float)hv[2], (float)hv[3]);
            float4 v1 = make_float4((float)hv[4], (float)hv[5], (float)hv[6], (float)hv[7]);
            *reinterpret_cast<float4*>(&Pl[r * PW + c8])     = v0;
            *reinterpret_cast<float4*>(&Pl[r * PW + c8 + 4]) = v1;
        }
        // stage W rows ecol0..ecol0+31 (coalesced float4)
#pragma unroll
        for (int i = 0; i < 4; ++i) {
            const int g  = t + 256 * i;     // 1024 float4 groups
            const int e  = g >> 5;
            const int k0 = (g & 31) * 4;
            *reinterpret_cast<float4*>(&Wl[e * PW + k0]) =
                *reinterpret_cast<const float4*>(W + (size_t)(ecol0 + e) * EMB + k0);
        }
        __syncthreads();

        const int rb = t >> 4;     // 0..15
        const int cb = t & 15;     // 0..15
        float acc00 = 0.f, acc01 = 0.f, acc10 = 0.f, acc11 = 0.f;
        for (int kk = 0; kk < EMB; kk += 4) {
            float4 a0 = *reinterpret_cast<const float4*>(&Pl[rb * PW + kk]);
            float4 a1 = *reinterpret_cast<const float4*>(&Pl[(rb + 16) * PW + kk]);
            float4 w0 = *reinterpret_cast<const float4*>(&Wl[cb * PW + kk]);
            float4 w1 = *reinterpret_cast<const float4*>(&Wl[(cb + 16) * PW + kk]);
            acc00 = fmaf(a0.x, w0.x, acc00); acc00 = fmaf(a0.y, w0.y, acc00);
            acc00 = fmaf(a0.z, w0.z, acc00); acc00 = fmaf(a0.w, w0.w, acc00);
            acc01 = fmaf(a0.x, w1.x, acc01); acc01 = fmaf(a0.y, w1.y, acc01);
            acc01 = fmaf(a0.z, w1.z, acc01); acc01 = fmaf(a0.w, w1.w, acc01);
            acc10 = fmaf(a1.x, w0.x, acc10); acc10 = fmaf(a1.y, w0.y, acc10);
            acc10 = fmaf(a1.z, w0.z, acc10); acc10 = fmaf(a1.w, w0.w, acc10);
            acc11 = fmaf(a1.x, w1.x, acc11); acc11 = fmaf(a1.y, w1.y, acc11);
            acc11 = fmaf(a1.z, w1.z, acc11); acc11 = fmaf(a1.w, w1.w, acc11);
        }

        const float b0 = bias[ecol0 + cb], b1 = bias[ecol0 + cb + 16];
        out[(size_t)(row0 + rb) * EMB + ecol0 + cb]           = acc00 + b0;
        out[(size_t)(row0 + rb) * EMB + ecol0 + cb + 16]      = acc01 + b1;
        out[(size_t)(row0 + rb + 16) * EMB + ecol0 + cb]      = acc10 + b0;
        out[(size_t)(row0 + rb + 16) * EMB + ecol0 + cb + 16] = acc11 + b1;
    }
}

// ---------------- fallback path (proven R6 two-kernel) -----------------------
__global__ __launch_bounds__(256, 4) void qattn_fb(
    const float* __restrict__ x,
    const float* __restrict__ theta,
    _Float16* __restrict__ P)
{
    __shared__ float kv[2 * SEQ * 4];
    const int t   = threadIdx.x;
    const int idx = blockIdx.x;
    const int qc  = idx & 15;
    const int bh  = idx >> 4;
    const int b   = bh >> 4, h = bh & 15;

    float th[8];
#pragma unroll
    for (int w = 0; w < 8; ++w) th[w] = theta[w];

#pragma unroll
    for (int i = 0; i < 4; ++i) {
        const int kl = t + 256 * i;
        float z[8];
        qrow(x + ((size_t)(b * SEQ + kl) * EMB + h * NW), th, z);
        *reinterpret_cast<float4*>(&kv[kl * 4])         = make_float4(z[0], z[1], z[2], z[3]);
        *reinterpret_cast<float4*>(&kv[(SEQ + kl) * 4]) = make_float4(z[4], z[5], z[6], z[7]);
    }

    const float QS = 0.35355339059327373f * 1.4426950408889634f;
    const int ql = t & 63;
    const int kh = t >> 6;
    const int sq = qc * 64 + ql;
    float qv[8], oacc[8];
    {
        float z[8];
        qrow(x + ((size_t)(b * SEQ + sq) * EMB + h * NW), th, z);
#pragma unroll
        for (int d = 0; d < 8; ++d) { qv[d] = z[d] * QS; oacc[d] = 0.f; }
    }
    float lac = 0.f;
    __syncthreads();

    const float4* kvA = reinterpret_cast<const float4*>(kv);
    const int k0 = kh * 256;
#pragma unroll 4
    for (int k = k0; k < k0 + 256; ++k) {
        float4 ka = kvA[k];
        float4 kb = kvA[SEQ + k];
        float s = fmaf(qv[0], ka.x, fmaf(qv[1], ka.y, fmaf(qv[2], ka.z, fmaf(qv[3], ka.w,
                  fmaf(qv[4], kb.x, fmaf(qv[5], kb.y, fmaf(qv[6], kb.z, qv[7] * kb.w)))))));
        float pe = __builtin_amdgcn_exp2f(s);
        lac += pe;
        oacc[0] = fmaf(pe, ka.x, oacc[0]); oacc[1] = fmaf(pe, ka.y, oacc[1]);
        oacc[2] = fmaf(pe, ka.z, oacc[2]); oacc[3] = fmaf(pe, ka.w, oacc[3]);
        oacc[4] = fmaf(pe, kb.x, oacc[4]); oacc[5] = fmaf(pe, kb.y, oacc[5]);
        oacc[6] = fmaf(pe, kb.z, oacc[6]); oacc[7] = fmaf(pe, kb.w, oacc[7]);
    }

    __syncthreads();
    float* red = kv;
#pragma unroll
    for (int d = 0; d < 8; ++d) red[t * 9 + d] = oacc[d];
    red[t * 9 + 8] = lac;
    __syncthreads();

    if (t < 64) {
        float o[8];
#pragma unroll
        for (int d = 0; d < 8; ++d) o[d] = red[t * 9 + d];
        float l = red[t * 9 + 8];
#pragma unroll
        for (int j = 1; j < 4; ++j) {
            const int base = (t + 64 * j) * 9;
#pragma unroll
            for (int d = 0; d < 8; ++d) o[d] += red[base + d];
            l += red[base + 8];
        }
        const float inv = 1.0f / l;
        half8 hv;
#pragma unroll
        for (int d = 0; d < 8; ++d) hv[d] = (_Float16)(o[d] * inv);
        const int row = b * SEQ + qc * 64 + t;
        *reinterpret_cast<half8*>(P + (size_t)row * EMB + h * NW) = hv;
    }
}

__global__ __launch_bounds__(256, 4) void proj_fb(
    const _Float16* __restrict__ P,
    const float* __restrict__ W,
    const float* __restrict__ bias,
    float* __restrict__ out)
{
    __shared__ float Pl[32 * PW];
    __shared__ float Wl[32 * PW];
    const int t     = threadIdx.x;
    const int row0  = blockIdx.x * 32;
    const int ecol0 = blockIdx.y * 32;

#pragma unroll
    for (int i = 0; i < 2; ++i) {
        const int g  = t + 256 * i;
        const int r  = g >> 4;
        const int c8 = (g & 15) * 8;
        half8 hv = *reinterpret_cast<const half8*>(P + (size_t)(row0 + r) * EMB + c8);
        float4 v0 = make_float4((float)hv[0], (float)hv[1], (float)hv[2], (float)hv[3]);
        float4 v1 = make_float4((float)hv[4], (float)hv[5], (float)hv[6], (float)hv[7]);
        *reinterpret_cast<float4*>(&Pl[r * PW + c8])     = v0;
        *reinterpret_cast<float4*>(&Pl[r * PW + c8 + 4]) = v1;
    }
#pragma unroll
    for (int i = 0; i < 4; ++i) {
        const int g  = t + 256 * i;
        const int e  = g >> 5;
        const int k0 = (g & 31) * 4;
        *reinterpret_cast<float4*>(&Wl[e * PW + k0]) =
            *reinterpret_cast<const float4*>(W + (size_t)(ecol0 + e) * EMB + k0);
    }
    __syncthreads();

    const int rb = t >> 4;
    const int cb = t & 15;
    float acc00 = 0.f, acc01 = 0.f, acc10 = 0.f, acc11 = 0.f;
    for (int kk = 0; kk < EMB; kk += 4) {
        float4 a0 = *reinterpret_cast<const float4*>(&Pl[rb * PW + kk]);
        float4 a1 = *reinterpret_cast<const float4*>(&Pl[(rb + 16) * PW + kk]);
        float4 w0 = *reinterpret_cast<const float4*>(&Wl[cb * PW + kk]);
        float4 w1 = *reinterpret_cast<const float4*>(&Wl[(cb + 16) * PW + kk]);
        acc00 = fmaf(a0.x, w0.x, acc00); acc00 = fmaf(a0.y, w0.y, acc00);
        acc00 = fmaf(a0.z, w0.z, acc00); acc00 = fmaf(a0.w, w0.w, acc00);
        acc01 = fmaf(a0.x, w1.x, acc01); acc01 = fmaf(a0.y, w1.y, acc01);
        acc01 = fmaf(a0.z, w1.z, acc01); acc01 = fmaf(a0.w, w1.w, acc01);
        acc10 = fmaf(a1.x, w0.x, acc10); acc10 = fmaf(a1.y, w0.y, acc10);
        acc10 = fmaf(a1.z, w0.z, acc10); acc10 = fmaf(a1.w, w0.w, acc10);
        acc11 = fmaf(a1.x, w1.x, acc11); acc11 = fmaf(a1.y, w1.y, acc11);
        acc11 = fmaf(a1.z, w1.z, acc11); acc11 = fmaf(a1.w, w1.w, acc11);
    }

    const float b0 = bias[ecol0 + cb], b1 = bias[ecol0 + cb + 16];
    out[(size_t)(row0 + rb) * EMB + ecol0 + cb]           = acc00 + b0;
    out[(size_t)(row0 + rb) * EMB + ecol0 + cb + 16]      = acc01 + b1;
    out[(size_t)(row0 + rb + 16) * EMB + ecol0 + cb]      = acc10 + b0;
    out[(size_t)(row0 + rb + 16) * EMB + ecol0 + cb + 16] = acc11 + b1;
}

extern "C" void kernel_launch(void* const* d_in, const int* in_sizes, int n_in,
                              void* d_out, int out_size, void* d_ws, size_t ws_size,
                              hipStream_t stream)
{
    const float* x     = (const float*)d_in[0];
    const float* theta = (const float*)d_in[1];
    const float* W     = (const float*)d_in[2];
    const float* bias  = (const float*)d_in[3];
    float* out = (float*)d_out;
    _Float16* P = (_Float16*)d_ws;       // 2 MB

    void* args[] = { (void*)&x, (void*)&theta, (void*)&W, (void*)&bias,
                     (void*)&P, (void*)&out };
    hipError_t err = hipLaunchCooperativeKernel(
        reinterpret_cast<const void*>(fused_attn_proj),
        dim3(1024), dim3(256), args, 0, stream);

    if (err != hipSuccess) {
        // deterministic fallback: proven two-kernel path
        qattn_fb<<<128 * 16, 256, 0, stream>>>(x, theta, P);
        proj_fb<<<dim3(BATCH * SEQ / 32, EMB / 32), 256, 0, stream>>>(P, W, bias, out);
    }
}

// Round 8
// 126.511 us; speedup vs baseline: 1.6409x; 1.6409x over previous
//
#include <hip/hip_runtime.h>

#define NHEADS 16
#define NW 8
#define SEQ 1024
#define BATCH 8
#define EMB 128
#define PW 132                 // proj LDS row stride (floats)

typedef __fp16 half2_t __attribute__((ext_vector_type(2)));
typedef __fp16 half8_t __attribute__((ext_vector_type(8)));

// quantum_heads closed form for one (b,s,head) row (fp32 input):
// c[w] = cos(x[w] + theta[w]); z[0] = c1..c7; z[w>=1] = c0..cw
__device__ __forceinline__ void qrow(const float* __restrict__ xp,
                                     const float* __restrict__ th, float* z) {
    float4 a = *reinterpret_cast<const float4*>(xp);
    float4 b = *reinterpret_cast<const float4*>(xp + 4);
    float c0 = __cosf(a.x + th[0]);
    float c1 = __cosf(a.y + th[1]);
    float c2 = __cosf(a.z + th[2]);
    float c3 = __cosf(a.w + th[3]);
    float c4 = __cosf(b.x + th[4]);
    float c5 = __cosf(b.y + th[5]);
    float c6 = __cosf(b.z + th[6]);
    float c7 = __cosf(b.w + th[7]);
    float u = c1 * c2;
    u *= c3; u *= c4; u *= c5; u *= c6; u *= c7;
    z[0] = u;
    z[1] = c0 * c1;
    z[2] = z[1] * c2;
    z[3] = z[2] * c3;
    z[4] = z[3] * c4;
    z[5] = z[4] * c5;
    z[6] = z[5] * c6;
    z[7] = z[6] * c7;
}

__device__ __forceinline__ float dot8_f16(const half2_t* qh, half2_t k0, half2_t k1,
                                          half2_t k2, half2_t k3) {
#if __has_builtin(__builtin_amdgcn_fdot2)
    return __builtin_amdgcn_fdot2(qh[3], k3,
           __builtin_amdgcn_fdot2(qh[2], k2,
           __builtin_amdgcn_fdot2(qh[1], k1,
           __builtin_amdgcn_fdot2(qh[0], k0, 0.0f, false), false), false), false);
#else
    float s = (float)qh[0][0] * (float)k0[0] + (float)qh[0][1] * (float)k0[1]
            + (float)qh[1][0] * (float)k1[0] + (float)qh[1][1] * (float)k1[1]
            + (float)qh[2][0] * (float)k2[0] + (float)qh[2][1] * (float)k2[1]
            + (float)qh[3][0] * (float)k3[0] + (float)qh[3][1] * (float)k3[1];
    return s;
#endif
}

// Kernel A: full attention for one (b,h, 64-query chunk) per block.
// Thread t: query t&63, key-quarter t>>6 (256 keys). All 1024 keys staged in
// LDS as f16 (16 KB -> 8 blocks/CU). Inner loop: 1 uniform ds_read_b128 +
// v_dot2 dot + v_pk_fma_f16 accumulate (f32 chunk flush every 32 keys).
// Epilogue: 4-way LDS reduce (reusing kv), normalize, write P as f16.
// grid = 128 bh * 16 qchunks = 2048 blocks.
__global__ __launch_bounds__(256, 8) void qattn(
    const float* __restrict__ x,
    const float* __restrict__ theta,
    __fp16* __restrict__ P)        // [B*S][128] f16, normalized attn@h
{
    __shared__ __align__(16) __fp16 kvh[SEQ * NW];   // 16 KB
    const int t   = threadIdx.x;
    const int idx = blockIdx.x;
    const int qc  = idx & 15;               // query chunk
    const int bh  = idx >> 4;               // 0..127
    const int b   = bh >> 4, h = bh & 15;

    float th[8];
#pragma unroll
    for (int w = 0; w < 8; ++w) th[w] = theta[w];   // wave-uniform -> s_loads

    // stage all 1024 keys as f16, 4 per thread (one b128 store each)
#pragma unroll
    for (int i = 0; i < 4; ++i) {
        const int kl = t + 256 * i;
        float z[8];
        qrow(x + ((size_t)(b * SEQ + kl) * EMB + h * NW), th, z);
        half8_t hv;
#pragma unroll
        for (int d = 0; d < 8; ++d) hv[d] = (__fp16)z[d];
        *reinterpret_cast<half8_t*>(&kvh[kl * 8]) = hv;
    }

    // this thread's query as 4 half2 (1/sqrt(8)*log2e folded -> exp2(s)==exp(score))
    const float QS = 0.35355339059327373f * 1.4426950408889634f;
    const int ql = t & 63;
    const int kh = t >> 6;
    const int sq = qc * 64 + ql;
    half2_t qh[4];
    float oacc[8], lac = 0.f;
    {
        float z[8];
        qrow(x + ((size_t)(b * SEQ + sq) * EMB + h * NW), th, z);
#pragma unroll
        for (int j = 0; j < 4; ++j) {
            qh[j][0] = (__fp16)(z[2 * j] * QS);
            qh[j][1] = (__fp16)(z[2 * j + 1] * QS);
        }
#pragma unroll
        for (int d = 0; d < 8; ++d) oacc[d] = 0.f;
    }

    __syncthreads();

    const half8_t* kp = reinterpret_cast<const half8_t*>(kvh) + kh * 256;
    for (int c = 0; c < 8; ++c) {           // 8 chunks x 32 keys
        half2_t oh0 = {0, 0}, oh1 = {0, 0}, oh2 = {0, 0}, oh3 = {0, 0};
#pragma unroll 4
        for (int k = 0; k < 32; ++k) {
            half8_t kk = kp[c * 32 + k];    // uniform address -> broadcast b128
            half2_t k0 = __builtin_shufflevector(kk, kk, 0, 1);
            half2_t k1 = __builtin_shufflevector(kk, kk, 2, 3);
            half2_t k2 = __builtin_shufflevector(kk, kk, 4, 5);
            half2_t k3 = __builtin_shufflevector(kk, kk, 6, 7);
            float s = dot8_f16(qh, k0, k1, k2, k3);
            float p = __builtin_amdgcn_exp2f(s);       // one v_exp_f32
            lac += p;
            half2_t ph = __builtin_amdgcn_cvt_pkrtz(p, p);
            oh0 = ph * k0 + oh0;            // v_pk_fma_f16
            oh1 = ph * k1 + oh1;
            oh2 = ph * k2 + oh2;
            oh3 = ph * k3 + oh3;
        }
        // flush chunk to f32 (limits f16 accumulation depth to 32)
        oacc[0] += (float)oh0[0]; oacc[1] += (float)oh0[1];
        oacc[2] += (float)oh1[0]; oacc[3] += (float)oh1[1];
        oacc[4] += (float)oh2[0]; oacc[5] += (float)oh2[1];
        oacc[6] += (float)oh3[0]; oacc[7] += (float)oh3[1];
    }

    __syncthreads();                 // all reads of kvh done -> reuse as reduce buf
    float* red = reinterpret_cast<float*>(kvh);   // [256][9] f32, odd stride
#pragma unroll
    for (int d = 0; d < 8; ++d) red[t * 9 + d] = oacc[d];
    red[t * 9 + 8] = lac;
    __syncthreads();

    if (t < 64) {
        float o[8];
#pragma unroll
        for (int d = 0; d < 8; ++d) o[d] = red[t * 9 + d];
        float l = red[t * 9 + 8];
#pragma unroll
        for (int j = 1; j < 4; ++j) {
            const int base = (t + 64 * j) * 9;
#pragma unroll
            for (int d = 0; d < 8; ++d) o[d] += red[base + d];
            l += red[base + 8];
        }
        const float inv = 1.0f / l;
        half8_t hv;
#pragma unroll
        for (int d = 0; d < 8; ++d) hv[d] = (__fp16)(o[d] * inv);
        const int row = b * SEQ + qc * 64 + t;
        *reinterpret_cast<half8_t*>(P + (size_t)row * EMB + h * NW) = hv;
    }
}

// Kernel B: out[row, e] = sum_f P[row,f] * W[e,f] + bias[e].  P is f16 [8192][128].
// grid = (8192/32) x (128/32) = 1024 blocks, 256 threads, 4 blocks/CU.
// 32x32 tile, 2x2 strided register tile (broadcast / 2-way LDS banking).
__global__ __launch_bounds__(256, 4) void proj_out(
    const __fp16* __restrict__ P,
    const float* __restrict__ W,
    const float* __restrict__ bias,
    float* __restrict__ out)
{
    __shared__ float Pl[32 * PW];             // 16.9 KB
    __shared__ float Wl[32 * PW];             // 16.9 KB
    const int t     = threadIdx.x;
    const int row0  = blockIdx.x * 32;
    const int ecol0 = blockIdx.y * 32;

    // stage P tile: 32 rows x 128 cols f16 -> f32 LDS (coalesced half8 loads)
#pragma unroll
    for (int i = 0; i < 2; ++i) {
        const int g  = t + 256 * i;           // 512 half8 chunks
        const int r  = g >> 4;
        const int c8 = (g & 15) * 8;
        half8_t hv = *reinterpret_cast<const half8_t*>(P + (size_t)(row0 + r) * EMB + c8);
        float4 v0 = make_float4((float)hv[0], (float)hv[1], (float)hv[2], (float)hv[3]);
        float4 v1 = make_float4((float)hv[4], (float)hv[5], (float)hv[6], (float)hv[7]);
        *reinterpret_cast<float4*>(&Pl[r * PW + c8])     = v0;
        *reinterpret_cast<float4*>(&Pl[r * PW + c8 + 4]) = v1;
    }
    // stage W rows ecol0..ecol0+31 (coalesced float4)
#pragma unroll
    for (int i = 0; i < 4; ++i) {
        const int g  = t + 256 * i;           // 1024 float4 groups
        const int e  = g >> 5;
        const int k0 = (g & 31) * 4;
        *reinterpret_cast<float4*>(&Wl[e * PW + k0]) =
            *reinterpret_cast<const float4*>(W + (size_t)(ecol0 + e) * EMB + k0);
    }
    __syncthreads();

    // compute: rows {rb, rb+16}, cols {cb, cb+16}
    const int rb = t >> 4;     // 0..15
    const int cb = t & 15;     // 0..15
    float acc00 = 0.f, acc01 = 0.f, acc10 = 0.f, acc11 = 0.f;
    for (int kk = 0; kk < EMB; kk += 4) {
        float4 a0 = *reinterpret_cast<const float4*>(&Pl[rb * PW + kk]);
        float4 a1 = *reinterpret_cast<const float4*>(&Pl[(rb + 16) * PW + kk]);
        float4 w0 = *reinterpret_cast<const float4*>(&Wl[cb * PW + kk]);
        float4 w1 = *reinterpret_cast<const float4*>(&Wl[(cb + 16) * PW + kk]);
        acc00 = fmaf(a0.x, w0.x, acc00); acc00 = fmaf(a0.y, w0.y, acc00);
        acc00 = fmaf(a0.z, w0.z, acc00); acc00 = fmaf(a0.w, w0.w, acc00);
        acc01 = fmaf(a0.x, w1.x, acc01); acc01 = fmaf(a0.y, w1.y, acc01);
        acc01 = fmaf(a0.z, w1.z, acc01); acc01 = fmaf(a0.w, w1.w, acc01);
        acc10 = fmaf(a1.x, w0.x, acc10); acc10 = fmaf(a1.y, w0.y, acc10);
        acc10 = fmaf(a1.z, w0.z, acc10); acc10 = fmaf(a1.w, w0.w, acc10);
        acc11 = fmaf(a1.x, w1.x, acc11); acc11 = fmaf(a1.y, w1.y, acc11);
        acc11 = fmaf(a1.z, w1.z, acc11); acc11 = fmaf(a1.w, w1.w, acc11);
    }

    const float b0 = bias[ecol0 + cb], b1 = bias[ecol0 + cb + 16];
    out[(size_t)(row0 + rb) * EMB + ecol0 + cb]           = acc00 + b0;
    out[(size_t)(row0 + rb) * EMB + ecol0 + cb + 16]      = acc01 + b1;
    out[(size_t)(row0 + rb + 16) * EMB + ecol0 + cb]      = acc10 + b0;
    out[(size_t)(row0 + rb + 16) * EMB + ecol0 + cb + 16] = acc11 + b1;
}

extern "C" void kernel_launch(void* const* d_in, const int* in_sizes, int n_in,
                              void* d_out, int out_size, void* d_ws, size_t ws_size,
                              hipStream_t stream)
{
    const float* x     = (const float*)d_in[0];
    const float* theta = (const float*)d_in[1];
    const float* W     = (const float*)d_in[2];
    const float* bias  = (const float*)d_in[3];
    float* out = (float*)d_out;

    __fp16* P = (__fp16*)d_ws;      // 2 MB

    qattn<<<128 * 16, 256, 0, stream>>>(x, theta, P);
    proj_out<<<dim3(BATCH * SEQ / 32, EMB / 32), 256, 0, stream>>>(P, W, bias, out);
}

// Round 11
// 92.785 us; speedup vs baseline: 2.2373x; 1.3635x over previous
//
#include <hip/hip_runtime.h>

#define NHEADS 16
#define NW 8
#define SEQ 1024
#define BATCH 8
#define EMB 128
#define PW 132                 // proj LDS row stride (floats)

typedef _Float16 half2_t __attribute__((ext_vector_type(2)));
typedef _Float16 half4_t __attribute__((ext_vector_type(4)));
typedef _Float16 half8_t __attribute__((ext_vector_type(8)));
typedef float    f32x4   __attribute__((ext_vector_type(4)));

__device__ __forceinline__ half2_t pkrtz(float a, float b) {
    return __builtin_bit_cast(half2_t, __builtin_amdgcn_cvt_pkrtz(a, b));
}

// qattn smem layout in halves:
//   kvh  [1024 keys][8 dims]            @ 0      (16 KB, row-major)
//   kvhT [8 dims][stride 1040]          @ 8192   (16.25 KB, transposed, padded)
//   ones [8]                            @ 16512
//   zero [8]                            @ 16520
#define KVT       8192
#define KVT_STR   1040
#define ONES_OFF  16512
#define ZERO_OFF  16520
#define SMEM_H    16544        // + pad for last-iteration prefetch overrun

// quantum_heads closed form for one (b,s,head) row (fp32 input):
// c[w] = cos(x[w] + theta[w]); z[0] = c1..c7; z[w>=1] = c0..cw
__device__ __forceinline__ void qrow(const float* __restrict__ xp,
                                     const float* __restrict__ th, float* z) {
    float4 a = *reinterpret_cast<const float4*>(xp);
    float4 b = *reinterpret_cast<const float4*>(xp + 4);
    float c0 = __cosf(a.x + th[0]);
    float c1 = __cosf(a.y + th[1]);
    float c2 = __cosf(a.z + th[2]);
    float c3 = __cosf(a.w + th[3]);
    float c4 = __cosf(b.x + th[4]);
    float c5 = __cosf(b.y + th[5]);
    float c6 = __cosf(b.z + th[6]);
    float c7 = __cosf(b.w + th[7]);
    float u = c1 * c2;
    u *= c3; u *= c4; u *= c5; u *= c6; u *= c7;
    z[0] = u;
    z[1] = c0 * c1;
    z[2] = z[1] * c2;
    z[3] = z[2] * c3;
    z[4] = z[3] * c4;
    z[5] = z[4] * c5;
    z[6] = z[5] * c6;
    z[7] = z[6] * c7;
}

// MFMA attention. grid = 128 bh * 8 qsplits = 1024 blocks, 256 threads.
// Per wave: 32 queries (2 q-tiles of 16). K-loop: 32 iters x 32 keys.
//   S^T = K.Q^T   (2x mfma 16x16x32 f16, d=8 zero-padded in K dim)
//   P   = exp2(S^T)  (QS*log2e folded into Q-frag)
//   O^T = Vx^T.P^T accumulated (Vx has ones col at dim 8 -> row-sum l)
// C->B transform: conflict-free 4-bpermute schedule (see derivation in notes):
//   source quads {0,2} publish (p0,p1,p2,p3), quads {1,3} publish (p2,p3,p0,p1);
//   target pulls iA=(q+(qd&1)*32+(qd>>1)*16), iB=iA^16; qd>=2 swaps (r0,r2),(r1,r3).
__global__ __launch_bounds__(256, 4) void qattn_mfma(
    const float* __restrict__ x,
    const float* __restrict__ theta,
    __fp16* __restrict__ P)        // [B*S][128] f16, normalized attn@h
{
    __shared__ __align__(16) _Float16 smem[SMEM_H];
    const int t   = threadIdx.x;
    const int bid = blockIdx.x;
    const int qs  = bid & 7;                // query octant (128 q)
    const int bh  = bid >> 3;               // 0..127
    const int b   = bh >> 4, h = bh & 15;

    float th[8];
#pragma unroll
    for (int w = 0; w < 8; ++w) th[w] = theta[w];   // wave-uniform -> s_loads

    // ---- stage all 1024 keys: row-major f16 + transposed copy ----
#pragma unroll
    for (int i = 0; i < 4; ++i) {
        const int kl = t + 256 * i;
        float z[8];
        qrow(x + ((size_t)(b * SEQ + kl) * EMB + h * NW), th, z);
        half8_t hv;
#pragma unroll
        for (int d = 0; d < 8; ++d) hv[d] = (_Float16)z[d];
        *reinterpret_cast<half8_t*>(&smem[kl * 8]) = hv;
#pragma unroll
        for (int d = 0; d < 8; ++d) smem[KVT + d * KVT_STR + kl] = hv[d];
    }
    if (t < 8)              smem[ONES_OFF + t]     = (_Float16)1.0f;
    else if (t < 16)        smem[ZERO_OFF + t - 8] = (_Float16)0.0f;
    __syncthreads();

    const int lane = t & 63;
    const int wv   = t >> 6;
    const int q16  = lane & 15;
    const int qd   = lane >> 4;             // quad 0..3
    const int qbase = qs * 128 + wv * 32;

    // ---- Q fragments (B operand): B[k=dim][n=q], quads!=0 read zeros ----
    const _Float16 QSh = (_Float16)0.51012924f;   // (1/sqrt(8))*log2(e)
    half8_t qfrag[2];
#pragma unroll
    for (int qi = 0; qi < 2; ++qi) {
        const _Float16* qp = (qd == 0)
            ? &smem[(qbase + qi * 16 + q16) * 8] : &smem[ZERO_OFF];
        half8_t qv = *reinterpret_cast<const half8_t*>(qp);
#pragma unroll
        for (int j = 0; j < 8; ++j) qv[j] = qv[j] * QSh;
        qfrag[qi] = qv;
    }

    // ---- loop-invariant pointers / lane constants ----
    const _Float16* ka = (qd == 0) ? &smem[q16 * 8]        : &smem[ZERO_OFF];
    const _Float16* kb = (qd == 0) ? &smem[(16 + q16) * 8] : &smem[ZERO_OFF];
    const int kstep = (qd == 0) ? 256 : 0;          // 32 keys * 8 halves
    const _Float16* vp; int vstep;
    if (q16 < 8)       { vp = &smem[KVT + q16 * KVT_STR + qd * 8]; vstep = 32; }
    else if (q16 == 8) { vp = &smem[ONES_OFF]; vstep = 0; }
    else               { vp = &smem[ZERO_OFF]; vstep = 0; }

    const bool oddq = (qd & 1);                         // source-side publication
    const bool hiC  = (qd >= 2);                        // dest-side swap
    const int  iA   = (q16 + (qd & 1) * 32 + (qd >> 1) * 16) * 4;
    const int  iB   = iA ^ 64;
    const int  lidx = (32 + q16) * 4;                   // lane holding dim-8 row (l)

    f32x4 oacc[2] = {{0.f, 0.f, 0.f, 0.f}, {0.f, 0.f, 0.f, 0.f}};
    const f32x4 zc = {0.f, 0.f, 0.f, 0.f};

    half8_t kA = *reinterpret_cast<const half8_t*>(ka);
    half8_t kB = *reinterpret_cast<const half8_t*>(kb);
    half8_t vA = *reinterpret_cast<const half8_t*>(vp);

    for (int kt = 0; kt < 32; ++kt) {
        ka += kstep; kb += kstep; vp += vstep;
        half8_t nkA = *reinterpret_cast<const half8_t*>(ka);   // prefetch (pad-safe)
        half8_t nkB = *reinterpret_cast<const half8_t*>(kb);
        half8_t nvA = *reinterpret_cast<const half8_t*>(vp);

#pragma unroll
        for (int qi = 0; qi < 2; ++qi) {
            // S^T tiles: C[row=key=qd*4+reg][col=q=lane&15]
            f32x4 c0 = __builtin_amdgcn_mfma_f32_16x16x32_f16(kA, qfrag[qi], zc, 0, 0, 0);
            f32x4 c1 = __builtin_amdgcn_mfma_f32_16x16x32_f16(kB, qfrag[qi], zc, 0, 0, 0);
            // p0/p1 = local keys 4qd+{0,1}/{2,3}; p2/p3 = keys 16+4qd+{0,1}/{2,3}
            half2_t p0 = pkrtz(__builtin_amdgcn_exp2f(c0[0]), __builtin_amdgcn_exp2f(c0[1]));
            half2_t p1 = pkrtz(__builtin_amdgcn_exp2f(c0[2]), __builtin_amdgcn_exp2f(c0[3]));
            half2_t p2 = pkrtz(__builtin_amdgcn_exp2f(c1[0]), __builtin_amdgcn_exp2f(c1[1]));
            half2_t p3 = pkrtz(__builtin_amdgcn_exp2f(c1[2]), __builtin_amdgcn_exp2f(c1[3]));
            union { half2_t h; int i; } u0, u1, u2, u3;
            u0.h = p0; u1.h = p1; u2.h = p2; u3.h = p3;
            // publication: quads {0,2} -> (p0,p1,p2,p3); quads {1,3} -> (p2,p3,p0,p1)
            const int a0 = oddq ? u2.i : u0.i;
            const int a1 = oddq ? u3.i : u1.i;
            const int a2 = oddq ? u0.i : u2.i;
            const int a3 = oddq ? u1.i : u3.i;
            const int r0 = __builtin_amdgcn_ds_bpermute(iA, a0);
            const int r1 = __builtin_amdgcn_ds_bpermute(iA, a1);
            const int r2 = __builtin_amdgcn_ds_bpermute(iB, a2);
            const int r3 = __builtin_amdgcn_ds_bpermute(iB, a3);
            // assemble B-operand P^T frag: element j = P[key=qd*8+j][q=lane&15]
            union { int i[4]; half8_t h; } bf;
            bf.i[0] = hiC ? r2 : r0;
            bf.i[1] = hiC ? r3 : r1;
            bf.i[2] = hiC ? r0 : r2;
            bf.i[3] = hiC ? r1 : r3;
            // O^T += Vx^T . P^T  (ones col -> row-sum l in dim 8)
            oacc[qi] = __builtin_amdgcn_mfma_f32_16x16x32_f16(vA, bf.h, oacc[qi], 0, 0, 0);
        }
        kA = nkA; kB = nkB; vA = nvA;
    }

    // ---- epilogue: normalize by l (row 8 = quad2 reg0), write P f16 ----
#pragma unroll
    for (int qi = 0; qi < 2; ++qi) {
        f32x4 c = oacc[qi];
        const float lsum = __int_as_float(
            __builtin_amdgcn_ds_bpermute(lidx, __float_as_int(c[0])));
        const float inv = 1.0f / lsum;
        if (qd < 2) {                       // quads 0,1 hold dims 0-7
            half2_t u0 = pkrtz(c[0] * inv, c[1] * inv);
            half2_t u1 = pkrtz(c[2] * inv, c[3] * inv);
            half4_t o4; o4[0] = u0[0]; o4[1] = u0[1]; o4[2] = u1[0]; o4[3] = u1[1];
            const int row = b * SEQ + qbase + qi * 16 + q16;
            *reinterpret_cast<half4_t*>(
                reinterpret_cast<_Float16*>(P) + (size_t)row * EMB + h * NW + qd * 4) = o4;
        }
    }
}

// Kernel B: out[row, e] = sum_f P[row,f] * W[e,f] + bias[e].  P is f16 [8192][128].
// grid = (8192/32) x (128/32) = 1024 blocks, 256 threads, 4 blocks/CU.
__global__ __launch_bounds__(256, 4) void proj_out(
    const __fp16* __restrict__ P,
    const float* __restrict__ W,
    const float* __restrict__ bias,
    float* __restrict__ out)
{
    __shared__ float Pl[32 * PW];             // 16.9 KB
    __shared__ float Wl[32 * PW];             // 16.9 KB
    const int t     = threadIdx.x;
    const int row0  = blockIdx.x * 32;
    const int ecol0 = blockIdx.y * 32;

#pragma unroll
    for (int i = 0; i < 2; ++i) {
        const int g  = t + 256 * i;           // 512 half8 chunks
        const int r  = g >> 4;
        const int c8 = (g & 15) * 8;
        half8_t hv = *reinterpret_cast<const half8_t*>(
            reinterpret_cast<const _Float16*>(P) + (size_t)(row0 + r) * EMB + c8);
        float4 v0 = make_float4((float)hv[0], (float)hv[1], (float)hv[2], (float)hv[3]);
        float4 v1 = make_float4((float)hv[4], (float)hv[5], (float)hv[6], (float)hv[7]);
        *reinterpret_cast<float4*>(&Pl[r * PW + c8])     = v0;
        *reinterpret_cast<float4*>(&Pl[r * PW + c8 + 4]) = v1;
    }
#pragma unroll
    for (int i = 0; i < 4; ++i) {
        const int g  = t + 256 * i;           // 1024 float4 groups
        const int e  = g >> 5;
        const int k0 = (g & 31) * 4;
        *reinterpret_cast<float4*>(&Wl[e * PW + k0]) =
            *reinterpret_cast<const float4*>(W + (size_t)(ecol0 + e) * EMB + k0);
    }
    __syncthreads();

    const int rb = t >> 4;     // 0..15
    const int cb = t & 15;     // 0..15
    float acc00 = 0.f, acc01 = 0.f, acc10 = 0.f, acc11 = 0.f;
    for (int kk = 0; kk < EMB; kk += 4) {
        float4 a0 = *reinterpret_cast<const float4*>(&Pl[rb * PW + kk]);
        float4 a1 = *reinterpret_cast<const float4*>(&Pl[(rb + 16) * PW + kk]);
        float4 w0 = *reinterpret_cast<const float4*>(&Wl[cb * PW + kk]);
        float4 w1 = *reinterpret_cast<const float4*>(&Wl[(cb + 16) * PW + kk]);
        acc00 = fmaf(a0.x, w0.x, acc00); acc00 = fmaf(a0.y, w0.y, acc00);
        acc00 = fmaf(a0.z, w0.z, acc00); acc00 = fmaf(a0.w, w0.w, acc00);
        acc01 = fmaf(a0.x, w1.x, acc01); acc01 = fmaf(a0.y, w1.y, acc01);
        acc01 = fmaf(a0.z, w1.z, acc01); acc01 = fmaf(a0.w, w1.w, acc01);
        acc10 = fmaf(a1.x, w0.x, acc10); acc10 = fmaf(a1.y, w0.y, acc10);
        acc10 = fmaf(a1.z, w0.z, acc10); acc10 = fmaf(a1.w, w0.w, acc10);
        acc11 = fmaf(a1.x, w1.x, acc11); acc11 = fmaf(a1.y, w1.y, acc11);
        acc11 = fmaf(a1.z, w1.z, acc11); acc11 = fmaf(a1.w, w1.w, acc11);
    }

    const float b0 = bias[ecol0 + cb], b1 = bias[ecol0 + cb + 16];
    out[(size_t)(row0 + rb) * EMB + ecol0 + cb]           = acc00 + b0;
    out[(size_t)(row0 + rb) * EMB + ecol0 + cb + 16]      = acc01 + b1;
    out[(size_t)(row0 + rb + 16) * EMB + ecol0 + cb]      = acc10 + b0;
    out[(size_t)(row0 + rb + 16) * EMB + ecol0 + cb + 16] = acc11 + b1;
}

extern "C" void kernel_launch(void* const* d_in, const int* in_sizes, int n_in,
                              void* d_out, int out_size, void* d_ws, size_t ws_size,
                              hipStream_t stream)
{
    const float* x     = (const float*)d_in[0];
    const float* theta = (const float*)d_in[1];
    const float* W     = (const float*)d_in[2];
    const float* bias  = (const float*)d_in[3];
    float* out = (float*)d_out;

    __fp16* P = (__fp16*)d_ws;      // 2 MB

    qattn_mfma<<<128 * 8, 256, 0, stream>>>(x, theta, P);
    proj_out<<<dim3(BATCH * SEQ / 32, EMB / 32), 256, 0, stream>>>(P, W, bias, out);
}